// Round 7
// baseline (710.672 us; speedup 1.0000x reference)
//
#include <hip/hip_runtime.h>
#include <hip/hip_fp16.h>

// LSTM B=256,T=512,IN=64,H=128,L=2 + FC -- SINGLE KERNEL.
// R7 = R6 + amdgpu_waves_per_eu(2,2). R6 post-mortem: compiler allocated
// 128 VGPRs (its heuristic targets 2 blocks/CU, ignoring that 151KB LDS
// already caps us at 1 block/CU = 2 waves/SIMD) and spilled ~80 regs ->
// WRITE_SIZE 63MB of scratch traffic, ~30% dead cycles. waves_per_eu(2,2)
// is occupancy-neutral here (launch IS 2 waves/EU) but unlocks the full
// 256-VGPR budget so B0/B1/W0p/acc/xs (~210 regs) stay resident.
//
// 256 blocks (1 batch) x 512 thr (8 waves). Wave w, lane (q=l>>4,c=l&15)
// owns unit = w*16+c. L1 lags L0 by CH=8 steps. Per chunk k (65 chunks):
//   8 step-iters:
//     L0-rec : gates0(k*8+j)     = h0(prev) @ Whh0^T + xg0t[j]  (Whh0: 64 VGPR)
//     L1-rec : gates1((k-1)*8+j) = h1(prev) @ Whh1^T + xg1t[j]  (Whh1: 64 VGPR)
//   then 2 GEMM phases + 1 barrier:
//     x-phase : xg0t <- x[b, chunk k+1, :64] @ Wih0^T + b0  (Wih0: 32 VGPR;
//               x global->reg issued at chunk TOP, ~8 steps of latency cover)
//     xg-phase: xg1t <- h0tile(chunk k) @ Wih1^T + b1       (Wih1: LDS 128KB,
//               chunk-XOR swizzled)
// k=0 runs L1 on zeroed xg1t/h1 (exact zero-dynamics); k=NCH runs L0 on
// bounded garbage (unconsumed). Broadcast-row MFMA trick: all 16 A-rows =
// h; lane holds its unit's gate quad in acc[g][0]; acc[1..3] stale.

#define TT 512
#define CH 8
#define NCH 64            // TT / CH
#define HP 136            // padded h0tile row stride (272B = 17*16, aligned)

typedef _Float16 f16x4 __attribute__((ext_vector_type(4)));
typedef _Float16 f16x8 __attribute__((ext_vector_type(8)));
typedef float f32x4 __attribute__((ext_vector_type(4)));

__device__ __forceinline__ float tanh_f(float x) {
    float e = __expf(2.0f * x);
    return 1.0f - 2.0f * __builtin_amdgcn_rcpf(e + 1.0f);
}
__device__ __forceinline__ float sigm_f(float x) {
    return __builtin_amdgcn_rcpf(1.0f + __expf(-x));
}
__device__ __forceinline__ f16x8 cvt8(float4 a, float4 b) {
    f16x8 f;
    f[0] = (_Float16)a.x; f[1] = (_Float16)a.y;
    f[2] = (_Float16)a.z; f[3] = (_Float16)a.w;
    f[4] = (_Float16)b.x; f[5] = (_Float16)b.y;
    f[6] = (_Float16)b.z; f[7] = (_Float16)b.w;
    return f;
}

__global__ __launch_bounds__(512)
__attribute__((amdgpu_waves_per_eu(2, 2)))
void lstm_full(
    const float* __restrict__ x,      // [B,T,64] f32
    const float* __restrict__ wih0, const float* __restrict__ whh0,
    const float* __restrict__ bih0, const float* __restrict__ bhh0,
    const float* __restrict__ wih1, const float* __restrict__ whh1,
    const float* __restrict__ bih1, const float* __restrict__ bhh1,
    const float* __restrict__ fc_w, const float* __restrict__ fc_b,
    float* __restrict__ out)
{
    const int t = threadIdx.x;
    const int b = blockIdx.x;
    const int w = t >> 6;
    const int l = t & 63;
    const int q = l >> 4;            // quad 0..3
    const int c = l & 15;
    const int unit = (w << 4) + c;   // 0..127

    __shared__ __align__(16) _Float16 w1lds[512 * 128];   // 128 KB
    __shared__ __align__(16) _Float16 xg0t[CH * 512];     //   8 KB
    __shared__ __align__(16) _Float16 xg1t[CH * 512];     //   8 KB
    __shared__ __align__(16) _Float16 h0tile[CH * HP];    // 2176 B
    __shared__ __align__(16) _Float16 h1buf[2][128];      //  512 B
    __shared__ float redbuf[128];                         //  512 B

    // ---- stage Wih1 -> LDS (one row/thread, cvt + chunk-XOR swizzle) ----
    {
        const int r = t;
        const float* src = wih1 + (size_t)r * 128;
        #pragma unroll
        for (int j = 0; j < 16; ++j)
            *(f16x8*)&w1lds[r * 128 + ((j ^ (r & 7)) << 3)] =
                cvt8(((const float4*)src)[2 * j], ((const float4*)src)[2 * j + 1]);
    }

    // ---- resident weight frags: Whh0/Whh1 (K=128), Wih0 (K=64) ----
    f16x8 B0[4][4], B1[4][4], W0p[4][2];
    #pragma unroll
    for (int g = 0; g < 4; ++g) {
        #pragma unroll
        for (int kt = 0; kt < 4; ++kt) {
            const size_t off = (size_t)((g << 7) + unit) * 128 + (kt << 5) + (q << 3);
            B0[g][kt] = cvt8(((const float4*)(whh0 + off))[0],
                             ((const float4*)(whh0 + off))[1]);
            B1[g][kt] = cvt8(((const float4*)(whh1 + off))[0],
                             ((const float4*)(whh1 + off))[1]);
        }
        #pragma unroll
        for (int kt = 0; kt < 2; ++kt) {
            const size_t off = (size_t)((g << 7) + unit) * 64 + (kt << 5) + (q << 3);
            W0p[g][kt] = cvt8(((const float4*)(wih0 + off))[0],
                              ((const float4*)(wih0 + off))[1]);
        }
    }
    float bias0g[4], bias1g[4];
    #pragma unroll
    for (int g = 0; g < 4; ++g) {
        bias0g[g] = bih0[(g << 7) + unit] + bhh0[(g << 7) + unit];
        bias1g[g] = bih1[(g << 7) + unit] + bhh1[(g << 7) + unit];
    }

    // zeros: xg1t (k=0 L1 zero-dynamics), h1buf, h0 ring slot CH-1.
    {
        int i = t;                                   // CH*512/8 = 512 f4 slots
        ((float4*)xg1t)[i] = make_float4(0.f, 0.f, 0.f, 0.f);
    }
    if (t < 128) {
        h1buf[0][t] = (_Float16)0.f;
        h1buf[1][t] = (_Float16)0.f;
        h0tile[(CH - 1) * HP + t] = (_Float16)0.f;
    }

    // ---- x chunk staging (global->reg; consumed by x-phase) ----
    float4 xs0, xs1, xs2, xs3;
    auto load_x = [&](int base) {
        const float* xp = x + ((size_t)b * TT + base + (c & 7)) * 64 + (q << 3);
        xs0 = ((const float4*)xp)[0];
        xs1 = ((const float4*)xp)[1];
        xs2 = ((const float4*)(xp + 32))[0];
        xs3 = ((const float4*)(xp + 32))[1];
    };
    // x-phase: xg0t[r][unit][4g] = x_chunk @ Wih0^T + b0
    auto xphase = [&]() {
        f32x4 G[4];
        #pragma unroll
        for (int g = 0; g < 4; ++g)
            G[g] = (f32x4){bias0g[g], bias0g[g], bias0g[g], bias0g[g]};
        f16x8 Ax0 = cvt8(xs0, xs1);
        f16x8 Ax1 = cvt8(xs2, xs3);
        #pragma unroll
        for (int g = 0; g < 4; ++g)
            G[g] = __builtin_amdgcn_mfma_f32_16x16x32_f16(Ax0, W0p[g][0], G[g], 0, 0, 0);
        #pragma unroll
        for (int g = 0; g < 4; ++g)
            G[g] = __builtin_amdgcn_mfma_f32_16x16x32_f16(Ax1, W0p[g][1], G[g], 0, 0, 0);
        #pragma unroll
        for (int i2 = 0; i2 < 4; ++i2) {   // D rows 8..15 dup rows 0..7
            f16x4 pk;
            pk[0] = (_Float16)G[0][i2]; pk[1] = (_Float16)G[1][i2];
            pk[2] = (_Float16)G[2][i2]; pk[3] = (_Float16)G[3][i2];
            *(f16x4*)&xg0t[((((q << 2) + i2) & 7) << 9) + (unit << 2)] = pk;
        }
    };
    // xg-phase: xg1t[r][unit][4g] = h0tile @ Wih1^T + b1
    auto xgphase = [&]() {
        f32x4 G[4];
        #pragma unroll
        for (int g = 0; g < 4; ++g)
            G[g] = (f32x4){bias1g[g], bias1g[g], bias1g[g], bias1g[g]};
        #pragma unroll
        for (int kt = 0; kt < 4; ++kt) {
            f16x8 Ah = *(const f16x8*)&h0tile[(c & 7) * HP + (kt << 5) + (q << 3)];
            #pragma unroll
            for (int g = 0; g < 4; ++g) {
                f16x8 Bg = *(const f16x8*)&w1lds[(((g << 7) + unit) << 7) +
                               ((((kt << 2) + q) ^ (c & 7)) << 3)];
                G[g] = __builtin_amdgcn_mfma_f32_16x16x32_f16(Ah, Bg, G[g], 0, 0, 0);
            }
        }
        #pragma unroll
        for (int i2 = 0; i2 < 4; ++i2) {
            f16x4 pk;
            pk[0] = (_Float16)G[0][i2]; pk[1] = (_Float16)G[1][i2];
            pk[2] = (_Float16)G[2][i2]; pk[3] = (_Float16)G[3][i2];
            *(f16x4*)&xg1t[((((q << 2) + i2) & 7) << 9) + (unit << 2)] = pk;
        }
    };

    // persistent accumulators; only [0] ever read (stale-lane trick).
    f32x4 a0[4], a1[4];
    #pragma unroll
    for (int g = 0; g < 4; ++g) {
        a0[g] = (f32x4){0.f, 0.f, 0.f, 0.f};
        a1[g] = (f32x4){0.f, 0.f, 0.f, 0.f};
    }
    float cst0 = 0.f, cst1 = 0.f;

    // prologue: chunk-0 x-phase (all LDS writes precede the single barrier)
    load_x(0);
    xphase();
    __syncthreads();

    #pragma unroll 1
    for (int k = 0; k <= NCH; ++k) {
        if (k < NCH - 1) load_x((k + 1) * CH);   // latency hidden by 8 steps

        #pragma unroll
        for (int j = 0; j < CH; ++j) {
            const int rp = (j + CH - 1) & (CH - 1);
            f16x4 xv  = *(const f16x4*)&xg0t[(j << 9) + (unit << 2)];
            f16x4 x1v = *(const f16x4*)&xg1t[(j << 9) + (unit << 2)];
            #pragma unroll
            for (int g = 0; g < 4; ++g) {
                a0[g][0] = (float)xv[g];
                a1[g][0] = (float)x1v[g];
            }
            #pragma unroll
            for (int kt = 0; kt < 4; ++kt) {
                f16x8 Af0 = *(const f16x8*)&h0tile[rp * HP + (kt << 5) + (q << 3)];
                f16x8 Af1 = *(const f16x8*)&h1buf[(j & 1) ^ 1][(kt << 5) + (q << 3)];
                #pragma unroll
                for (int g = 0; g < 4; ++g)
                    a0[g] = __builtin_amdgcn_mfma_f32_16x16x32_f16(Af0, B0[g][kt], a0[g], 0, 0, 0);
                #pragma unroll
                for (int g = 0; g < 4; ++g)
                    a1[g] = __builtin_amdgcn_mfma_f32_16x16x32_f16(Af1, B1[g][kt], a1[g], 0, 0, 0);
            }
            {   // L0 activation (k=NCH: bounded garbage, unconsumed)
                float gi = sigm_f(a0[0][0]);
                float gf = sigm_f(a0[1][0]);
                float gg = tanh_f(a0[2][0]);
                float go = sigm_f(a0[3][0]);
                cst0 = gf * cst0 + gi * gg;
                float hh = go * tanh_f(cst0);
                if (l < 16) h0tile[j * HP + unit] = (_Float16)hh;
            }
            {   // L1 activation (k=0: exact zero-dynamics)
                float gi = sigm_f(a1[0][0]);
                float gf = sigm_f(a1[1][0]);
                float gg = tanh_f(a1[2][0]);
                float go = sigm_f(a1[3][0]);
                cst1 = gf * cst1 + gi * gg;
                float hh = go * tanh_f(cst1);
                if (l < 16) {
                    h1buf[j & 1][unit] = (_Float16)hh;
                    if (j == CH - 1) redbuf[unit] = hh;   // last chunk's wins
                }
            }
            __syncthreads();
        }

        if (k < NCH) {
            if (k < NCH - 1) xphase();   // xg0 for chunk k+1
            xgphase();                   // xg1 from h0tile(chunk k)
            __syncthreads();
        }
    }

    // fused FC on h1(T-1)
    if (t < 64) {
        float p = redbuf[t] * fc_w[t] + redbuf[t + 64] * fc_w[t + 64];
        #pragma unroll
        for (int off = 32; off > 0; off >>= 1) p += __shfl_down(p, off, 64);
        if (t == 0) out[b] = p + fc_b[0];
    }
}

extern "C" void kernel_launch(void* const* d_in, const int* in_sizes, int n_in,
                              void* d_out, int out_size, void* d_ws, size_t ws_size,
                              hipStream_t stream) {
    const float* x     = (const float*)d_in[0];
    const float* w_ih0 = (const float*)d_in[1];
    const float* w_hh0 = (const float*)d_in[2];
    const float* b_ih0 = (const float*)d_in[3];
    const float* b_hh0 = (const float*)d_in[4];
    const float* w_ih1 = (const float*)d_in[5];
    const float* w_hh1 = (const float*)d_in[6];
    const float* b_ih1 = (const float*)d_in[7];
    const float* b_hh1 = (const float*)d_in[8];
    const float* fc_w  = (const float*)d_in[9];
    const float* fc_b  = (const float*)d_in[10];
    float* out = (float*)d_out;
    (void)d_ws; (void)ws_size;

    lstm_full<<<dim3(256), dim3(512), 0, stream>>>(
        x, w_ih0, w_hh0, b_ih0, b_hh0,
        w_ih1, w_hh1, b_ih1, b_hh1, fc_w, fc_b, out);
}

// Round 8
// 643.186 us; speedup vs baseline: 1.1049x; 1.1049x over previous
//
#include <hip/hip_runtime.h>
#include <hip/hip_fp16.h>

// LSTM B=256,T=512,IN=64,H=128,L=2 + FC.
//  K0 cvt  : w_ih0 -> fp16 (tiny)
//  KG      : xg0 = x(f32).Wih0^T + bias -> [B*T][unit][4g] f16 (fused cvt)
//  KF      : both recurrent layers (L1 lags CH=8) + chunked xg1 GEMM + FC
//
// R8: R6 single-kernel demand (~270 regs) exceeded the unified 256-reg/wave
// ceiling at 2 waves/SIMD -> loop-resident scratch spill (63MB WRITE_SIZE),
// and waves_per_eu couldn't fix a hard ceiling. This round cuts demand to
// ~235 by moving the x-projection back to a standalone GEMM (deletes W0p/
// xs/bias0g = 48 regs) and reading xg0 per-step as one 8B global load with
// depth-2 rotating prefetch (regs xr[4], compile-time indexed).
// KF per chunk k (65 chunks, CH=8):
//   8 steps: L0-rec gates0 = h0@Whh0^T + xg0[s] (B0: 64 VGPR)
//            L1-rec gates1 = h1@Whh1^T + xg1t[j] (B1: 64 VGPR), lag 8
//   xg-phase: xg1t <- h0tile @ Wih1^T + b1 (Wih1: 128KB LDS, XOR-swizzled)
// Broadcast-row MFMA: all 16 A-rows = h; lane (q,c) of wave w holds the
// gate quad of unit w*16+c in acc[g][0]; acc[1..3] permanently stale.

#define TT 512
#define CH 8
#define NCH 64            // TT / CH
#define MM (256 * 512)
#define HP 136            // padded h0tile row stride

typedef _Float16 f16x4 __attribute__((ext_vector_type(4)));
typedef _Float16 f16x8 __attribute__((ext_vector_type(8)));
typedef float f32x4 __attribute__((ext_vector_type(4)));

__device__ __forceinline__ float tanh_f(float x) {
    float e = __expf(2.0f * x);
    return 1.0f - 2.0f * __builtin_amdgcn_rcpf(e + 1.0f);
}
__device__ __forceinline__ float sigm_f(float x) {
    return __builtin_amdgcn_rcpf(1.0f + __expf(-x));
}
__device__ __forceinline__ f16x8 cvt8(float4 a, float4 b) {
    f16x8 f;
    f[0] = (_Float16)a.x; f[1] = (_Float16)a.y;
    f[2] = (_Float16)a.z; f[3] = (_Float16)a.w;
    f[4] = (_Float16)b.x; f[5] = (_Float16)b.y;
    f[6] = (_Float16)b.z; f[7] = (_Float16)b.w;
    return f;
}

// ---------------- K0: fp32 -> fp16 cvt (vector4) ----------------
__global__ void cvt_f32_f16(const float* __restrict__ src,
                            _Float16* __restrict__ dst, int n4) {
    int i = blockIdx.x * blockDim.x + threadIdx.x;
    int stride = gridDim.x * blockDim.x;
    for (; i < n4; i += stride) {
        float4 v = ((const float4*)src)[i];
        f16x4 a;
        a[0] = (_Float16)v.x; a[1] = (_Float16)v.y;
        a[2] = (_Float16)v.z; a[3] = (_Float16)v.w;
        ((f16x4*)dst)[i] = a;
    }
}

// ------- KG: xg[M][u][4g] = A32[M,64] . W[512,64]^T + (bih+bhh) ----------
__global__ __launch_bounds__(256, 1) void gemm_xg0(
    const float* __restrict__ A32, const _Float16* __restrict__ W,
    const float* __restrict__ bih, const float* __restrict__ bhh,
    _Float16* __restrict__ out)
{
    const int l  = threadIdx.x & 63;
    const int w  = threadIdx.x >> 6;
    const int mb = blockIdx.x * 64 + w * 16;
    const int c  = l & 15;
    const int q  = l >> 4;

    __shared__ float biasl[512];
    for (int i = threadIdx.x; i < 512; i += 256) biasl[i] = bih[i] + bhh[i];
    __syncthreads();

    f32x4 C[32];
    #pragma unroll
    for (int i = 0; i < 32; ++i) C[i] = (f32x4){0.f, 0.f, 0.f, 0.f};

    #pragma unroll
    for (int ks = 0; ks < 2; ++ks) {
        const float* ap = A32 + (size_t)(mb + c) * 64 + ks * 32 + q * 8;
        f16x8 Af = cvt8(((const float4*)ap)[0], ((const float4*)ap)[1]);
        #pragma unroll
        for (int nt = 0; nt < 32; ++nt) {
            f16x8 Bf = *(const f16x8*)(W + (size_t)(nt * 16 + c) * 64 + ks * 32 + q * 8);
            C[nt] = __builtin_amdgcn_mfma_f32_16x16x32_f16(Af, Bf, C[nt], 0, 0, 0);
        }
    }
    #pragma unroll
    for (int uu = 0; uu < 8; ++uu) {
        float b0 = biasl[uu * 16 + c];
        float b1 = biasl[128 + uu * 16 + c];
        float b2 = biasl[256 + uu * 16 + c];
        float b3 = biasl[384 + uu * 16 + c];
        #pragma unroll
        for (int i = 0; i < 4; ++i) {
            int row = mb + q * 4 + i;
            f16x4 pk;
            pk[0] = (_Float16)(C[uu][i]      + b0);
            pk[1] = (_Float16)(C[8 + uu][i]  + b1);
            pk[2] = (_Float16)(C[16 + uu][i] + b2);
            pk[3] = (_Float16)(C[24 + uu][i] + b3);
            ((f16x4*)out)[(size_t)row * 128 + uu * 16 + c] = pk;
        }
    }
}

// ---------------- KF: fused two-layer recurrence + chunked xgate + FC -----
__global__
__attribute__((amdgpu_flat_work_group_size(512, 512), amdgpu_waves_per_eu(2, 2)))
void lstm_fused(
    const float* __restrict__ whh0, const float* __restrict__ wih1,
    const float* __restrict__ whh1,
    const float* __restrict__ bih1, const float* __restrict__ bhh1,
    const _Float16* __restrict__ xg0,   // [B*T][unit][4g] fp16 (bias incl.)
    const float* __restrict__ fc_w, const float* __restrict__ fc_b,
    float* __restrict__ out)
{
    const int t = threadIdx.x;
    const int b = blockIdx.x;
    const int w = t >> 6;
    const int l = t & 63;
    const int q = l >> 4;            // quad 0..3
    const int c = l & 15;
    const int unit = (w << 4) + c;   // 0..127

    __shared__ __align__(16) _Float16 w1lds[512 * 128];   // 128 KB
    __shared__ __align__(16) _Float16 xg1t[CH * 512];     //   8 KB
    __shared__ __align__(16) _Float16 h0tile[CH * HP];    // 2176 B
    __shared__ __align__(16) _Float16 h1buf[2][128];      //  512 B
    __shared__ float redbuf[128];                         //  512 B

    // ---- stage Wih1 -> LDS (one row/thread, cvt + chunk-XOR swizzle) ----
    {
        const int r = t;
        const float* src = wih1 + (size_t)r * 128;
        #pragma unroll
        for (int j = 0; j < 16; ++j)
            *(f16x8*)&w1lds[r * 128 + ((j ^ (r & 7)) << 3)] =
                cvt8(((const float4*)src)[2 * j], ((const float4*)src)[2 * j + 1]);
    }

    // ---- resident B-frags: Whh0/Whh1 rows g*128+unit, k = kt*32+q*8 ----
    f16x8 B0[4][4], B1[4][4];
    #pragma unroll
    for (int g = 0; g < 4; ++g) {
        #pragma unroll
        for (int kt = 0; kt < 4; ++kt) {
            const size_t off = (size_t)((g << 7) + unit) * 128 + (kt << 5) + (q << 3);
            B0[g][kt] = cvt8(((const float4*)(whh0 + off))[0],
                             ((const float4*)(whh0 + off))[1]);
            B1[g][kt] = cvt8(((const float4*)(whh1 + off))[0],
                             ((const float4*)(whh1 + off))[1]);
        }
    }
    float bias1g[4];
    #pragma unroll
    for (int g = 0; g < 4; ++g)
        bias1g[g] = bih1[(g << 7) + unit] + bhh1[(g << 7) + unit];

    // zeros: xg1t (k=0 L1 zero-dynamics), h1buf, h0 ring slot CH-1.
    {
        int i = t;                                   // CH*512/8 = 512 f4 slots
        ((float4*)xg1t)[i] = make_float4(0.f, 0.f, 0.f, 0.f);
    }
    if (t < 128) {
        h1buf[0][t] = (_Float16)0.f;
        h1buf[1][t] = (_Float16)0.f;
        h0tile[(CH - 1) * HP + t] = (_Float16)0.f;
    }

    // xg0 rotating prefetch regs (depth 2, compile-time indexed).
    const f16x4* __restrict__ xgp = (const f16x4*)xg0 + (size_t)b * TT * 128 + unit;
    f16x4 xr[4];
    xr[0] = xgp[0];
    xr[1] = xgp[128];
    xr[2] = xr[0]; xr[3] = xr[0];   // overwritten before first use

    // persistent accumulators; only [0] ever read (stale-lane trick).
    f32x4 a0[4], a1[4];
    #pragma unroll
    for (int g = 0; g < 4; ++g) {
        a0[g] = (f32x4){0.f, 0.f, 0.f, 0.f};
        a1[g] = (f32x4){0.f, 0.f, 0.f, 0.f};
    }
    float cst0 = 0.f, cst1 = 0.f;
    __syncthreads();

    #pragma unroll 1
    for (int k = 0; k <= NCH; ++k) {
        #pragma unroll
        for (int j = 0; j < CH; ++j) {
            const int rp = (j + CH - 1) & (CH - 1);
            f16x4 xv  = xr[j & 3];
            f16x4 x1v = *(const f16x4*)&xg1t[(j << 9) + (unit << 2)];
            #pragma unroll
            for (int g = 0; g < 4; ++g) {
                a0[g][0] = (float)xv[g];
                a1[g][0] = (float)x1v[g];
            }
            // prefetch xg0 for step s+2 (OOB at tail lands in ws slack)
            xr[(j + 2) & 3] = xgp[(size_t)(k * CH + j + 2) * 128];

            #pragma unroll
            for (int kt = 0; kt < 4; ++kt) {
                f16x8 Af0 = *(const f16x8*)&h0tile[rp * HP + (kt << 5) + (q << 3)];
                f16x8 Af1 = *(const f16x8*)&h1buf[(j & 1) ^ 1][(kt << 5) + (q << 3)];
                #pragma unroll
                for (int g = 0; g < 4; ++g)
                    a0[g] = __builtin_amdgcn_mfma_f32_16x16x32_f16(Af0, B0[g][kt], a0[g], 0, 0, 0);
                #pragma unroll
                for (int g = 0; g < 4; ++g)
                    a1[g] = __builtin_amdgcn_mfma_f32_16x16x32_f16(Af1, B1[g][kt], a1[g], 0, 0, 0);
            }
            {   // L0 activation (k=NCH: bounded garbage, unconsumed)
                float gi = sigm_f(a0[0][0]);
                float gf = sigm_f(a0[1][0]);
                float gg = tanh_f(a0[2][0]);
                float go = sigm_f(a0[3][0]);
                cst0 = gf * cst0 + gi * gg;
                float hh = go * tanh_f(cst0);
                if (l < 16) h0tile[j * HP + unit] = (_Float16)hh;
            }
            {   // L1 activation (k=0: exact zero-dynamics)
                float gi = sigm_f(a1[0][0]);
                float gf = sigm_f(a1[1][0]);
                float gg = tanh_f(a1[2][0]);
                float go = sigm_f(a1[3][0]);
                cst1 = gf * cst1 + gi * gg;
                float hh = go * tanh_f(cst1);
                if (l < 16) {
                    h1buf[j & 1][unit] = (_Float16)hh;
                    if (j == CH - 1) redbuf[unit] = hh;   // last chunk's wins
                }
            }
            __syncthreads();
        }

        // ---- xg-phase: xg1t = h0tile(chunk k) @ Wih1^T + b1 ----
        if (k < NCH) {
            f32x4 G[4];
            #pragma unroll
            for (int g = 0; g < 4; ++g)
                G[g] = (f32x4){bias1g[g], bias1g[g], bias1g[g], bias1g[g]};
            #pragma unroll
            for (int kt = 0; kt < 4; ++kt) {
                f16x8 Ah = *(const f16x8*)&h0tile[(c & 7) * HP + (kt << 5) + (q << 3)];
                #pragma unroll
                for (int g = 0; g < 4; ++g) {
                    f16x8 Bg = *(const f16x8*)&w1lds[(((g << 7) + unit) << 7) +
                                   ((((kt << 2) + q) ^ (c & 7)) << 3)];
                    G[g] = __builtin_amdgcn_mfma_f32_16x16x32_f16(Ah, Bg, G[g], 0, 0, 0);
                }
            }
            #pragma unroll
            for (int i2 = 0; i2 < 4; ++i2) {   // D rows 8..15 dup rows 0..7
                f16x4 pk;
                pk[0] = (_Float16)G[0][i2]; pk[1] = (_Float16)G[1][i2];
                pk[2] = (_Float16)G[2][i2]; pk[3] = (_Float16)G[3][i2];
                *(f16x4*)&xg1t[((((q << 2) + i2) & 7) << 9) + (unit << 2)] = pk;
            }
            __syncthreads();
        }
    }

    // fused FC on h1(T-1)
    if (t < 64) {
        float p = redbuf[t] * fc_w[t] + redbuf[t + 64] * fc_w[t + 64];
        #pragma unroll
        for (int off = 32; off > 0; off >>= 1) p += __shfl_down(p, off, 64);
        if (t == 0) out[b] = p + fc_b[0];
    }
}

extern "C" void kernel_launch(void* const* d_in, const int* in_sizes, int n_in,
                              void* d_out, int out_size, void* d_ws, size_t ws_size,
                              hipStream_t stream) {
    const float* x     = (const float*)d_in[0];
    const float* w_ih0 = (const float*)d_in[1];
    const float* w_hh0 = (const float*)d_in[2];
    const float* b_ih0 = (const float*)d_in[3];
    const float* b_hh0 = (const float*)d_in[4];
    const float* w_ih1 = (const float*)d_in[5];
    const float* w_hh1 = (const float*)d_in[6];
    const float* b_ih1 = (const float*)d_in[7];
    const float* b_hh1 = (const float*)d_in[8];
    const float* fc_w  = (const float*)d_in[9];
    const float* fc_b  = (const float*)d_in[10];
    float* out = (float*)d_out;

    // ws layout: xg [134217728] + 64KB prefetch slack + w0_16 [65536]
    char* ws = (char*)d_ws;
    _Float16* xg    = (_Float16*)(ws);
    _Float16* w0_16 = (_Float16*)(ws + 134217728 + 65536);

    cvt_f32_f16<<<dim3(32), dim3(256), 0, stream>>>(w_ih0, w0_16, (512 * 64) / 4);

    gemm_xg0<<<dim3(MM / 64), dim3(256), 0, stream>>>(x, w0_16, b_ih0, b_hh0, xg);

    lstm_fused<<<dim3(256), dim3(512), 0, stream>>>(w_hh0, w_ih1, w_hh1,
                                                    b_ih1, b_hh1, xg,
                                                    fc_w, fc_b, out);
}